// Round 5
// baseline (418.484 us; speedup 1.0000x reference)
//
#include <hip/hip_runtime.h>

// Fusedmax: out = sparsemax(prox_TV1D(x, alpha=1)) row-wise. B=4096, N=512, fp32.
//
// v6: EVENT-DRIVEN wave-parallel Condat. Post-mortem of v3-v5 showed a ~215us
// floor no per-step model explains; the missing factor is Condat's rescans
// (jump -> restart at km+1 re-walks the stretch; in drift regimes each output
// element costs a whole re-scan). Between events (jumps/clamps) the recursion
// is closed-form in prefix sums C:
//   A_p = umin_q + (C_p - C_q) - (p-q)*vmin   (neg-jump: A_p < -lam, clamp-min: A_p >= lam)
//   B_p = umax_q + (C_p - C_q) - (p-q)*vmax   (pos-jump: B_p > lam, clamp-max: B_p <= -lam)
// (telescoped: jump tests use u(p-1)+y_p which collapses to the same A_p/B_p).
// So all 64 lanes probe 64 consecutive positions at once; ballot -> first
// event -> apply analytically. Rescans cost ~1 probe instead of a re-walk.
// Event sequence (priorities neg>pos>clamps, end-phase, rewind handling) is
// EXACTLY the reference's; only arithmetic is reassociated via prefix sums.
// Segments -> v4-verified deferred replay; Michelot sparsemax unchanged.

#define TVN 512
#define LAMBDA 1.0f
#define NSEG_MAX 768

__device__ __forceinline__ float wave_reduce_sum(float v) {
#pragma unroll
    for (int off = 32; off > 0; off >>= 1) v += __shfl_xor(v, off, 64);
    return v;
}

__global__ __launch_bounds__(64) void fusedmax_kernel(const float* __restrict__ xin,
                                                      float* __restrict__ out) {
    __shared__ alignas(16) float C[TVN];       // prefix sums; later reused as TV output
    __shared__ int   segi[NSEG_MAX];           // (k0 << 16) | end
    __shared__ float segv[NSEG_MAX];

    const int t = threadIdx.x;                 // 0..63
    const long long r = blockIdx.x;
    const float lam = LAMBDA;
    const float twolam = 2.0f * lam;

    // ---- stage row (8 consecutive elems per lane) + wave-parallel inclusive scan ----
    const float4* __restrict__ g4 = (const float4*)(xin + r * TVN);
    float4 a4 = g4[2 * t];
    float4 b4 = g4[2 * t + 1];
    float r0 = a4.x;
    float r1 = r0 + a4.y;
    float r2 = r1 + a4.z;
    float r3 = r2 + a4.w;
    float r4 = r3 + b4.x;
    float r5 = r4 + b4.y;
    float r6 = r5 + b4.z;
    float r7 = r6 + b4.w;
    float run = r7;
#pragma unroll
    for (int off = 1; off < 64; off <<= 1) {
        float nv = __shfl_up(run, off, 64);
        if (t >= off) run += nv;
    }
    const float excl = run - r7;               // exclusive prefix of lane totals
    const int base = 8 * t;
    C[base + 0] = excl + r0;
    C[base + 1] = excl + r1;
    C[base + 2] = excl + r2;
    C[base + 3] = excl + r3;
    C[base + 4] = excl + r4;
    C[base + 5] = excl + r5;
    C[base + 6] = excl + r6;
    C[base + 7] = excl + r7;
    __syncthreads();

    // ---- event-driven Condat scan: ALL lanes, state redundant per lane ----
    int q = 0, k0 = 0, km = 0, kp = 0, ns = 0, rw = 0;
    const float y0 = C[0];
    float vmin = y0 - lam, vmax = y0 + lam;
    float uminq = lam, umaxq = -lam;           // umin/umax at position q
    float Cq = y0;                             // C[q]
    int guard = 0;

    for (;;) {
        if (++guard > 30000) break;            // watchdog (never hit on sane data)

        if (q == TVN - 1) {                    // ---- end phase (reference-exact) ----
            if (uminq < 0.0f) {                // end-phase negative jump
                if (t == 0 && ns < NSEG_MAX) { segi[ns] = (k0 << 16) | km; segv[ns] = vmin; }
                ++ns;
                int nk = km + 1;
                if (nk < k0) rw = 1;
                if (nk > TVN - 1) nk = TVN - 1;
                const float c2 = C[nk], c1 = C[nk - 1];
                const float ynk = c2 - c1;     // pristine y[nk]
                q = nk; k0 = nk; km = nk;      // kp, vmax kept (reference)
                const float ov = vmax;
                vmin = ynk; uminq = lam; umaxq = ynk + lam - ov; Cq = c2;
                continue;
            }
            if (umaxq > 0.0f) {                // end-phase positive jump
                if (t == 0 && ns < NSEG_MAX) { segi[ns] = (k0 << 16) | kp; segv[ns] = vmax; }
                ++ns;
                int nk = kp + 1;
                if (nk < k0) rw = 1;
                if (nk > TVN - 1) nk = TVN - 1;
                const float c2 = C[nk], c1 = C[nk - 1];
                const float ynk = c2 - c1;
                q = nk; k0 = nk; kp = nk;      // km, vmin kept (reference)
                const float ov = vmin;
                vmax = ynk; umaxq = -lam; uminq = ynk - lam - ov; Cq = c2;
                continue;
            }
            {                                  // finish
                const float v = vmin + uminq / (float)(q - k0 + 1);
                if (t == 0 && ns < NSEG_MAX) { segi[ns] = (k0 << 16) | (TVN - 1); segv[ns] = v; }
                ++ns;
                break;
            }
        }

        // ---- 64-wide probe for the first event after q ----
        const int p = q + 1 + t;
        const int pv = (p < TVN) ? p : (TVN - 1);
        const float Wp = C[pv] - Cq;
        const float d = (float)(t + 1);        // p - q
        const float A = uminq + Wp - d * vmin;
        const float B = umaxq + Wp - d * vmax;
        const bool valid = (p <= TVN - 1);
        const bool ev = valid && ((A < -lam) || (A >= lam) || (B > lam) || (B <= -lam));
        const unsigned long long m = __ballot(ev);

        if (m == 0ULL) {                       // no event in window: closed-form advance
            const int qn = (q + 64 < TVN - 1) ? (q + 64) : (TVN - 1);
            const int li = qn - q - 1;         // lane holding A/B at qn
            uminq = __shfl(A, li);
            umaxq = __shfl(B, li);
            Cq = __shfl(Wp, li) + Cq;
            q = qn;
            continue;
        }

        const int pe = __ffsll(m) - 1;         // first event lane
        const int ps = q + 1 + pe;             // first event position
        const float As = __shfl(A, pe);
        const float Bs = __shfl(B, pe);
        const float Ws = __shfl(Wp, pe);

        if (As < -lam) {                       // negative jump at ps (priority 1)
            if (t == 0 && ns < NSEG_MAX) { segi[ns] = (k0 << 16) | km; segv[ns] = vmin; }
            ++ns;
            int nk = km + 1;
            if (nk < k0) rw = 1;
            if (nk > TVN - 1) nk = TVN - 1;
            const float c2 = C[nk], c1 = C[nk - 1];
            const float ynk = c2 - c1;
            q = nk; k0 = nk; km = nk; kp = nk;
            vmin = ynk; vmax = ynk + twolam; uminq = lam; umaxq = -lam; Cq = c2;
        } else if (Bs > lam) {                 // positive jump at ps (priority 2)
            if (t == 0 && ns < NSEG_MAX) { segi[ns] = (k0 << 16) | kp; segv[ns] = vmax; }
            ++ns;
            int nk = kp + 1;
            if (nk < k0) rw = 1;
            if (nk > TVN - 1) nk = TVN - 1;
            const float c2 = C[nk], c1 = C[nk - 1];
            const float ynk = c2 - c1;
            q = nk; k0 = nk; km = nk; kp = nk;
            vmax = ynk; vmin = ynk - twolam; uminq = lam; umaxq = -lam; Cq = c2;
        } else {                               // clamp(s) at ps: advance q -> ps
            const float cnt = (float)(ps - k0 + 1);
            const float rc = __builtin_amdgcn_rcpf(cnt);
            if (As >= lam) { vmin += (As - lam) * rc; uminq = lam; km = ps; }
            else           { uminq = As; }
            if (Bs <= -lam) { vmax += (Bs + lam) * rc; umaxq = -lam; kp = ps; }
            else            { umaxq = Bs; }
            q = ps; Cq = Ws + Cq;
        }
    }
    __syncthreads();

    // ---- segment replay: wave writes TV result into C ----
    {
        const int n = (ns < NSEG_MAX) ? ns : NSEG_MAX;
        if (rw == 0) {
            for (int s = t; s < n; s += 64) {   // disjoint -> one lane per segment
                const int pk = segi[s];
                const float v = segv[s];
                const int i1 = pk & 0xffff;
                for (int i = (pk >> 16); i <= i1; ++i) C[i] = v;
            }
        } else {
            for (int s = 0; s < n; ++s) {       // rare rewind -> chronological
                const int pk = segi[s];
                const float v = segv[s];
                const int i1 = pk & 0xffff;
                for (int i = (pk >> 16) + t; i <= i1; i += 64) C[i] = v;
            }
        }
    }
    __syncthreads();

    // ---- sparsemax via Michelot fixed point (exact tau, no sort) ----
    const float4* s4 = (const float4*)C;
    float4 a = s4[t];
    float4 b = s4[t + 64];
    float v[8] = {a.x, a.y, a.z, a.w, b.x, b.y, b.z, b.w};

    float ls = v[0] + v[1] + v[2] + v[3] + v[4] + v[5] + v[6] + v[7];
    float S = wave_reduce_sum(ls);
    float tau = (S - 1.0f) * (1.0f / (float)TVN);   // support = all
    int cprev = TVN;
#pragma unroll 1
    for (int it = 0; it < 64; ++it) {
        float s = 0.0f, c = 0.0f;
#pragma unroll
        for (int j = 0; j < 8; ++j) {
            if (v[j] > tau) { s += v[j]; c += 1.0f; }
        }
        s = wave_reduce_sum(s);
        c = wave_reduce_sum(c);               // >= 1 always (tau < max)
        tau = (s - 1.0f) / c;
        int ci = (int)c;
        if (ci == cprev) break;               // support stabilized -> tau exact
        cprev = ci;
    }

    float4 oa, ob;
    oa.x = fmaxf(v[0] - tau, 0.0f);
    oa.y = fmaxf(v[1] - tau, 0.0f);
    oa.z = fmaxf(v[2] - tau, 0.0f);
    oa.w = fmaxf(v[3] - tau, 0.0f);
    ob.x = fmaxf(v[4] - tau, 0.0f);
    ob.y = fmaxf(v[5] - tau, 0.0f);
    ob.z = fmaxf(v[6] - tau, 0.0f);
    ob.w = fmaxf(v[7] - tau, 0.0f);
    float4* __restrict__ o4 = (float4*)(out + r * TVN);
    o4[t] = oa;
    o4[t + 64] = ob;
}

extern "C" void kernel_launch(void* const* d_in, const int* in_sizes, int n_in,
                              void* d_out, int out_size, void* d_ws, size_t ws_size,
                              hipStream_t stream) {
    const float* x = (const float*)d_in[0];
    float* out = (float*)d_out;
    const int rows = in_sizes[0] / TVN;       // 4096
    fusedmax_kernel<<<dim3(rows), dim3(64), 0, stream>>>(x, out);
}

// Round 6
// 283.409 us; speedup vs baseline: 1.4766x; 1.4766x over previous
//
#include <hip/hip_runtime.h>

// Fusedmax: out = sparsemax(prox_TV1D(x, alpha=1)) row-wise. B=4096, N=512, fp32.
//
// v7: one wave per row, lane-0 Condat scan, v4 skeleton (deferred segment
// replay, double-buffered register batches, tail + end-phase, Michelot
// sparsemax). Cycle-ledger across v1-v6 closed on BRANCH-RESOLUTION HAZARDS
// (~14cy per v_cmp->vcc->s_cbranch, 4-5 per step in v3/v4) plus v5's hidden
// register spill (RC16 precompute pushed live floats past the allocation).
// v7's step has exactly ONE data-dependent branch:
//  - jump test:  fminf(t1 - vminl, vmaxl - t2) < 0  -> single v_cmp + branch
//    (pure VALU combine; cold path re-disambiguates, neg priority first).
//  - clamps: VALU-only predication (v_cmp + v_cndmask, no SALU hazard) using
//    v5's verified arithmetic: vmin += fmax(d1,0)*rcp(cnt) adds exact 0.0
//    when not firing; cnt = cntb + J (batch-base float + literal). No RC16.
//  - batch of 8 (not 16): 16 live batch floats + state ~ 35 VGPR, spill-safe.
// Event semantics (priorities neg>pos>clamps, end-phase, rewind) identical to
// the verified v4; clamp math identical to the verified v5.

#define TVN 512
#define LAMBDA 1.0f
#define NSEG_MAX 768

__device__ __forceinline__ float wave_reduce_sum(float v) {
#pragma unroll
    for (int off = 32; off > 0; off >>= 1) v += __shfl_xor(v, off, 64);
    return v;
}

#define LOAD8(P, B)                                                          \
    {                                                                        \
        const int _lb = (B);                                                 \
        P##0 = row[_lb + 0]; P##1 = row[_lb + 1];                            \
        P##2 = row[_lb + 2]; P##3 = row[_lb + 3];                            \
        P##4 = row[_lb + 4]; P##5 = row[_lb + 5];                            \
        P##6 = row[_lb + 6]; P##7 = row[_lb + 7];                            \
    }

// One Condat step at position p = b + J, consuming yn = row[b + J] (in W).
// One branch (jump test); clamps are VALU-predicated (exact 0.0 when idle).
#define STEP(W, J)                                                           \
    {                                                                        \
        const float t1 = (W) + umin;                                         \
        const float t2 = (W) + umax;                                         \
        if (__builtin_expect((int)(fminf(t1 - vminl, vmaxl - t2) < 0.0f), 0)) { \
            if (t1 < vminl) goto neg_jump; else goto pos_jump;               \
        }                                                                    \
        const float umin_t = t1 - vmin;                                      \
        const float umax_t = t2 - vmax;                                      \
        const float rc = __builtin_amdgcn_rcpf(cntb + (float)(J));           \
        const float d1 = umin_t - lam;                                       \
        const float d2 = umax_t + lam;                                       \
        vmin += fmaxf(d1, 0.0f) * rc;                                        \
        vmax += fminf(d2, 0.0f) * rc;                                        \
        vminl = vmin - lam;                                                  \
        vmaxl = vmax + lam;                                                  \
        umin = fminf(umin_t, lam);                                           \
        umax = fmaxf(umax_t, -lam);                                          \
        km = (d1 >= 0.0f) ? (b + (J)) : km;                                  \
        kp = (d2 <= 0.0f) ? (b + (J)) : kp;                                  \
    }

#define STEP8(P)                                                             \
    STEP(P##0, 0) STEP(P##1, 1) STEP(P##2, 2) STEP(P##3, 3)                  \
    STEP(P##4, 4) STEP(P##5, 5) STEP(P##6, 6) STEP(P##7, 7)

#define SETV_NEG()                                                           \
    vmin = ynk; vmax = ynk + twolam; umin = lam; umax = -lam;                 \
    vminl = vmin - lam; vmaxl = vmax + lam;

#define SETV_POS()                                                           \
    vmax = ynk; vmin = ynk - twolam; umin = lam; umax = -lam;                 \
    vminl = vmin - lam; vmaxl = vmax + lam;

__global__ __launch_bounds__(64) void fusedmax_kernel(const float* __restrict__ xin,
                                                      float* __restrict__ out) {
    __shared__ alignas(16) float row[TVN + 16];   // +16 pad: prefetch over-read only
    __shared__ int   segi[NSEG_MAX];              // (k0 << 16) | end
    __shared__ float segv[NSEG_MAX];
    __shared__ int nsS, rwS;

    const int t = threadIdx.x;                 // 0..63
    const long long r = blockIdx.x;
    const float lam = LAMBDA;

    // ---- stage row into LDS, coalesced (16B/lane) ----
    const float4* __restrict__ g4 = (const float4*)(xin + r * TVN);
    float4* s4 = (float4*)row;
    s4[t] = g4[t];
    s4[t + 64] = g4[t + 64];
    if (t < 16) row[TVN + t] = 0.0f;           // pad (loaded speculatively, never consumed)
    __syncthreads();

    // ---- Condat 1-D TV denoise, serial on lane 0, row stays PRISTINE ----
    if (t == 0) {
        const float twolam = 2.0f * lam;
        int k, k0, km, kp, b, ns, rewound, nk;
        float vmin, vmax, umin, umax, vminl, vmaxl, ynk, cntb;
        float wa0, wa1, wa2, wa3, wa4, wa5, wa6, wa7;
        float wb0, wb1, wb2, wb3, wb4, wb5, wb6, wb7;

        k = 0; k0 = 0; km = 0; kp = 0; ns = 0; rewound = 0;
        vmin = row[0] - lam; vmax = row[0] + lam;
        umin = lam; umax = -lam;
        vminl = vmin - lam; vmaxl = vmax + lam;
        goto refill;

    refill:                                    // generic re-entry: state current, k < TVN-1
        b = k + 1;
        cntb = (float)(k - k0 + 2);            // count at batch offset 0
        if (b > TVN - 9) goto tail;
        LOAD8(wa, b);
        goto fastA;

    fastA:                                     // wa holds row[b..b+7]
        LOAD8(wb, b + 8);                      // prefetch next batch
        STEP8(wa);
        b += 8; cntb += 8.0f;
        if (b > TVN - 9) { k = b - 1; goto tail; }
        goto fastB;

    fastB:                                     // wb holds row[b..b+7]
        LOAD8(wa, b + 8);
        STEP8(wb);
        b += 8; cntb += 8.0f;
        if (b > TVN - 9) { k = b - 1; goto tail; }
        goto fastA;

    neg_jump:
        segi[ns] = (k0 << 16) | km; segv[ns] = vmin; ++ns;
        nk = km + 1;
        if (nk < k0) rewound = 1;              // rewind (stale km after end-phase pos)
        if (nk > TVN - 1) nk = TVN - 1;
        ynk = row[nk];
        k = k0 = km = kp = nk;
        if (nk == TVN - 1) { SETV_NEG(); goto end_phase; }
        b = nk + 1; cntb = 2.0f;
        if (b > TVN - 9) { SETV_NEG(); goto tail; }
        LOAD8(wa, b);                          // batch loads in flight with ynk
        SETV_NEG();
        goto fastA;

    pos_jump:
        segi[ns] = (k0 << 16) | kp; segv[ns] = vmax; ++ns;
        nk = kp + 1;
        if (nk < k0) rewound = 1;              // rewind (stale kp after end-phase neg)
        if (nk > TVN - 1) nk = TVN - 1;
        ynk = row[nk];
        k = k0 = km = kp = nk;
        if (nk == TVN - 1) { SETV_POS(); goto end_phase; }
        b = nk + 1; cntb = 2.0f;
        if (b > TVN - 9) { SETV_POS(); goto tail; }
        LOAD8(wa, b);
        SETV_POS();
        goto fastA;

    tail:                                      // per-step with end checks; k <= TVN-2 on entry
        for (;;) {
            const float yn = row[k + 1];
            const float t1 = yn + umin;
            if (t1 < vminl) goto neg_jump;
            const float t2 = yn + umax;
            if (t2 > vmaxl) goto pos_jump;
            ++k;
            umin = t1 - vmin;
            umax = t2 - vmax;
            if (umin >= lam) {
                const float e = (umin - lam) * __builtin_amdgcn_rcpf((float)(k - k0 + 1));
                vmin += e; vminl = vmin - lam; umin = lam; km = k;
            }
            if (umax <= -lam) {
                const float e = (umax + lam) * __builtin_amdgcn_rcpf((float)(k - k0 + 1));
                vmax += e; vmaxl = vmax + lam; umax = -lam; kp = k;
            }
            if (k == TVN - 1) goto end_phase;
        }

    end_phase:                                 // k == TVN-1
        for (;;) {
            if (umin < 0.0f) {                 // end-phase negative jump
                segi[ns] = (k0 << 16) | km; segv[ns] = vmin; ++ns;
                nk = km + 1;
                if (nk < k0) rewound = 1;
                if (nk > TVN - 1) nk = TVN - 1;
                ynk = row[nk];                 // pristine row == reference's y
                k = k0 = km = nk;              // kp, vmax, vmaxl unchanged (reference)
                vmin = ynk; umin = lam; umax = ynk + lam - vmax;
                vminl = vmin - lam;
                if (k == TVN - 1) continue;
                goto refill;
            }
            if (umax > 0.0f) {                 // end-phase positive jump
                segi[ns] = (k0 << 16) | kp; segv[ns] = vmax; ++ns;
                nk = kp + 1;
                if (nk < k0) rewound = 1;
                if (nk > TVN - 1) nk = TVN - 1;
                ynk = row[nk];
                k = k0 = kp = nk;              // km, vmin, vminl unchanged (reference)
                vmax = ynk; umax = -lam; umin = ynk - lam - vmin;
                vmaxl = vmax + lam;
                if (k == TVN - 1) continue;
                goto refill;
            }
            {                                  // finish
                const float v = vmin + umin / (float)(k - k0 + 1);
                segi[ns] = (k0 << 16) | (TVN - 1); segv[ns] = v; ++ns;
                goto scan_done;
            }
        }

    scan_done:
        nsS = ns; rwS = rewound;
    }
    __syncthreads();

    // ---- segment replay: whole wave writes the TV result into row ----
    {
        const int n = nsS;
        if (rwS == 0) {
            // segments disjoint -> parallel: one lane per segment
            for (int s = t; s < n; s += 64) {
                const int pk = segi[s];
                const float v = segv[s];
                const int i1 = pk & 0xffff;
                for (int i = (pk >> 16); i <= i1; ++i) row[i] = v;
            }
        } else {
            // rare rewind -> chronological: wave-cooperative per segment, in order
            for (int s = 0; s < n; ++s) {
                const int pk = segi[s];
                const float v = segv[s];
                const int i1 = pk & 0xffff;
                for (int i = (pk >> 16) + t; i <= i1; i += 64) row[i] = v;
            }
        }
    }
    __syncthreads();

    // ---- sparsemax via Michelot fixed point (exact tau, no sort) ----
    float4 a = s4[t];
    float4 b = s4[t + 64];
    float v[8] = {a.x, a.y, a.z, a.w, b.x, b.y, b.z, b.w};

    float ls = v[0] + v[1] + v[2] + v[3] + v[4] + v[5] + v[6] + v[7];
    float S = wave_reduce_sum(ls);
    float tau = (S - 1.0f) * (1.0f / (float)TVN);   // support = all
    int cprev = TVN;
#pragma unroll 1
    for (int it = 0; it < 64; ++it) {
        float s = 0.0f, c = 0.0f;
#pragma unroll
        for (int j = 0; j < 8; ++j) {
            if (v[j] > tau) { s += v[j]; c += 1.0f; }
        }
        s = wave_reduce_sum(s);
        c = wave_reduce_sum(c);               // >= 1 always (tau < max)
        tau = (s - 1.0f) / c;
        int ci = (int)c;
        if (ci == cprev) break;               // support stabilized -> tau exact
        cprev = ci;
    }

    float4 oa, ob;
    oa.x = fmaxf(v[0] - tau, 0.0f);
    oa.y = fmaxf(v[1] - tau, 0.0f);
    oa.z = fmaxf(v[2] - tau, 0.0f);
    oa.w = fmaxf(v[3] - tau, 0.0f);
    ob.x = fmaxf(v[4] - tau, 0.0f);
    ob.y = fmaxf(v[5] - tau, 0.0f);
    ob.z = fmaxf(v[6] - tau, 0.0f);
    ob.w = fmaxf(v[7] - tau, 0.0f);
    float4* __restrict__ o4 = (float4*)(out + r * TVN);
    o4[t] = oa;
    o4[t + 64] = ob;
}

extern "C" void kernel_launch(void* const* d_in, const int* in_sizes, int n_in,
                              void* d_out, int out_size, void* d_ws, size_t ws_size,
                              hipStream_t stream) {
    const float* x = (const float*)d_in[0];
    float* out = (float*)d_out;
    const int rows = in_sizes[0] / TVN;       // 4096
    fusedmax_kernel<<<dim3(rows), dim3(64), 0, stream>>>(x, out);
}